// Round 6
// baseline (410.335 us; speedup 1.0000x reference)
//
#include <hip/hip_runtime.h>

// TBConv2d: BN -> ternary{-1,0,1} -> conv3x3(p=1) -> +bias -> ReLU
// v6: BARRIER-FREE wave-private pipelines.
// R5 post-mortem: time pinned at 103-122us across 4 different barrier
// schedules while traffic varied 240-330 MB -> not BW-bound, not pipe-bound;
// waves spend ~85% idle in lockstepped barrier round-trips. Fix: each wave
// owns a PRIVATE 18-px ring (its 16-px output strip + halo) and free-runs
// its own load->quant->scatter->ds_read->MFMA pipeline. Zero barriers in
// the main loop (within-wave LDS ordering is lgkmcnt, compiler-managed).
// ct-pair waves redundantly quantize the same pixels (L2 hits; VALU has 7x
// headroom). Two startup __syncthreads protect the weight-staging alias.
//  - wave = (xh: strip half, ct: co half); per wave: 16px x 16co x 32rows
//  - ring: 4 slots x 20 px-chunks x 64B = 5120 B/wave (4 waves = 20.5 KB,
//    weight staging 18.4 KB aliased inside)
//  - per row: 5 float2 loads, 10 quant-pairs, 10 u16 ds_writes,
//    9 ds_read_b128, 9 MFMA, 4 stores; prefetch row y+2 (ping-pong bufs)
//  - validity via NaN: invalid x-pairs get NaN scale/shift, invalid rows
//    load NaN -> quant1(NaN)=0 with no branches in scatter
//  - XCD band swizzle kept (bx%8 = yc: all strips of a band on one L2)

#define B_    16
#define H_    256
#define W_    256
#define ROWB  1280          // 20 px slots (18 real + 2 trash) * 64 B
#define WLDS  (4 * ROWB)    // 4-slot ring per wave = 5120 B

typedef __bf16 bf16x8 __attribute__((ext_vector_type(8)));
typedef float  f32x4  __attribute__((ext_vector_type(4)));
union FragCast { int4 i; bf16x8 b; };

__device__ __forceinline__ unsigned short f2bf(float f) {
    union { float f; unsigned u; } c; c.f = f;
    unsigned u = c.u;
    u += 0x7FFFu + ((u >> 16) & 1u);      // RNE
    return (unsigned short)(u >> 16);
}

// torch semantics @thr=0: x <= -0 -> -1 (catches 0), else x >= 0 -> +1, NaN -> 0
__device__ __forceinline__ unsigned short quant1(float v, float sc, float sh) {
    float xh = __fadd_rn(__fmul_rn(v, sc), sh);   // exact numpy op order, no FMA
    return (xh <= 0.0f) ? (unsigned short)0xBF80u
         : ((xh >= 0.0f) ? (unsigned short)0x3F80u : (unsigned short)0u);
}

__launch_bounds__(256, 4)
__global__ void tbconv_kernel(const float* __restrict__ x,
                              const float* __restrict__ bn_g,
                              const float* __restrict__ bn_b,
                              const float* __restrict__ bn_m,
                              const float* __restrict__ bn_v,
                              const float* __restrict__ conv_w,
                              const float* __restrict__ conv_b,
                              float* __restrict__ out)
{
    // [0,18432) holds bf16 weights [tap][co][ci] during init, then the
    // region becomes 4 private per-wave rings (4 * 5120 = 20480 B).
    __shared__ __align__(16) unsigned char smem[4 * WLDS];
    __shared__ float sScale[32], sShift[32];
    unsigned int* sW = (unsigned int*)smem;

    const int tid = threadIdx.x;
    const int bx  = blockIdx.x;
    // bx = strip*128 + b*8 + yc -> bx%8 = yc: all 8 strips of a (b,yc) band
    // share one XCD/L2 (halo + redundant ct-pair reads become L2 hits).
    const int strip = bx >> 7;
    const int b     = (bx >> 3) & 15;
    const int yc    = bx & 7;
    const int y0    = yc * 32;

    if (tid < 32) {
        float s = __fdiv_rn(bn_g[tid], __fsqrt_rn(__fadd_rn(bn_v[tid], 1e-4f)));
        sScale[tid] = s;
        sShift[tid] = __fsub_rn(bn_b[tid], __fmul_rn(bn_m[tid], s));
    }
    // stage weights: sW dword j = [t][co][ci-pair]
    for (int j = tid; j < 4608; j += 256) {
        int cp = j & 15, co = (j >> 4) & 31, t = j >> 9;
        float w0 = conv_w[(co * 32 + 2 * cp)     * 9 + t];
        float w1 = conv_w[(co * 32 + 2 * cp + 1) * 9 + t];
        sW[j] = (unsigned)f2bf(w0) | ((unsigned)f2bf(w1) << 16);
    }
    __syncthreads();

    const int lane = tid & 63, wave = tid >> 6;
    const int oct = lane >> 4, n = lane & 15;
    const int xh = wave >> 1, ct = wave & 1;
    const int x0w = strip * 32 + xh * 16;

    // persistent A-frags: A[m=co=ct*16+n][k=ci=oct*8+j] per tap
    FragCast fA[9];
    #pragma unroll
    for (int t = 0; t < 9; ++t)
        fA[t].i = *(const int4*)((const char*)smem +
                                 ((t * 32 + ct * 16 + n) * 32 + oct * 8) * 2);

    // ---- per-wave loader: 5 items, i = lane + 64j -> (ci = i/10, pr = i%10)
    // item loads aligned float2 at gx = x0w-2+2*pr; elements map to ring px
    // hx0 = 2pr-1, hx1 = 2pr (hx: 0..17 real, 18/19 trash).
    unsigned loff[5], lwp[5];
    float lsc[5], lsh[5];
    #pragma unroll
    for (int j = 0; j < 5; ++j) {
        int i = lane + 64 * j;
        int ci = i / 10, pr = i - 10 * ci;
        int gx = x0w - 2 + 2 * pr;
        bool xok = (gx >= 0) && (gx <= 254);
        int gxc = (gx < 0) ? 0 : ((gx > 254) ? 254 : gx);
        loff[j] = ((unsigned)(b * 32 + ci) << 18) + (unsigned)gxc * 4u;  // bytes
        int hx0 = 2 * pr - 1, hx1 = 2 * pr;
        int hc0 = (hx0 < 0)  ? 18 : hx0;         // trash slots, never read
        int hc1 = (hx1 > 17) ? 19 : hx1;
        int q = ci >> 3, cl = ci & 7;
        // chunk-level XOR swizzle: phys chunk = hx*4 + (cioct ^ ((hx>>1)&3))
        unsigned w0 = (unsigned)(((hc0 * 4 + (q ^ ((hc0 >> 1) & 3))) << 4) + cl * 2);
        unsigned w1 = (unsigned)(((hc1 * 4 + (q ^ ((hc1 >> 1) & 3))) << 4) + cl * 2);
        lwp[j] = w0 | (w1 << 16);
        float sc = sScale[ci], sh = sShift[ci];
        if (!xok) { sc = __int_as_float(0x7FC00000); sh = sc; }  // NaN -> quant 0
        lsc[j] = sc; lsh[j] = sh;
    }

    // per-lane B-frag offsets within a ring slot (hx = n + kw)
    char* ringp = (char*)smem + wave * WLDS;
    int dsoff[3];
    #pragma unroll
    for (int kw = 0; kw < 3; ++kw) {
        int hx = n + kw;
        dsoff[kw] = (hx * 4 + (oct ^ ((hx >> 1) & 3))) << 4;
    }

    float bias[4];
    #pragma unroll
    for (int r = 0; r < 4; ++r)
        bias[r] = conv_b[ct * 16 + oct * 4 + r];
    const size_t obase = (((size_t)(b * 32 + ct * 16 + oct * 4)) << 16)
                       + ((size_t)y0 << 8) + (x0w + n);

    // all fA ds_reads (any wave, full 18.4 KB span) must finish before any
    // wave's ring writes overwrite the alias. Last barrier in the kernel.
    __syncthreads();

    const char* xb = (const char*)x;
    auto load_row = [&](float2 (&dv)[5], int gy) {
        const bool yok = ((unsigned)gy < (unsigned)H_);
        const float nf = __int_as_float(0x7FC00000);
        #pragma unroll
        for (int j = 0; j < 5; ++j) {
            dv[j] = make_float2(nf, nf);         // NaN -> quant 0 (y padding)
            if (yok) dv[j] = *(const float2*)(xb + loff[j] + ((unsigned)gy << 10));
        }
    };
    auto scatter = [&](const float2 (&sv)[5], int slot) {
        char* rowp = ringp + slot * ROWB;
        #pragma unroll
        for (int j = 0; j < 5; ++j) {
            unsigned short q0 = quant1(sv[j].x, lsc[j], lsh[j]);
            unsigned short q1 = quant1(sv[j].y, lsc[j], lsh[j]);
            *(unsigned short*)(rowp + (lwp[j] & 0xFFFFu)) = q0;
            *(unsigned short*)(rowp + (lwp[j] >> 16))     = q1;
        }
    };

    // ---- prologue (private ring, within-wave order only, no syncs):
    // rows -1 -> slot 3, 0 -> slot 0; row 1 in buf1 (scattered at step 0)
    float2 buf0[5], buf1[5];
    load_row(buf0, y0 - 1);
    load_row(buf1, y0);
    scatter(buf0, 3);
    scatter(buf1, 0);
    load_row(buf1, y0 + 1);

    // ---- main loop: 32 rows, ZERO barriers. step y: load row y+2 into
    // buf[y&1]; scatter row y+1 from buf[(y+1)&1] to slot (y+1)&3;
    // compute row y from slots (y-1..y+1)&3; store.
    for (int t8 = 0; t8 < 8; ++t8) {
        #pragma unroll
        for (int u = 0; u < 4; ++u) {
            const int y  = t8 * 4 + u;       // 0..31, y&3 == u
            const int gy = y0 + y;

            if (y <= 30) {
                if ((u & 1) == 0) load_row(buf0, gy + 2);
                else              load_row(buf1, gy + 2);
            }
            if ((u & 1) == 0) scatter(buf1, (u + 1) & 3);
            else              scatter(buf0, (u + 1) & 3);

            f32x4 acc[3];
            #pragma unroll
            for (int kh = 0; kh < 3; ++kh) {
                const int sb = ((u + 3 + kh) & 3) * ROWB;   // slot(y-1+kh)
                FragCast fB[3];
                #pragma unroll
                for (int kw = 0; kw < 3; ++kw)
                    fB[kw].i = *(const int4*)(ringp + sb + dsoff[kw]);
                f32x4 a = {0.f, 0.f, 0.f, 0.f};
                #pragma unroll
                for (int kw = 0; kw < 3; ++kw)
                    a = __builtin_amdgcn_mfma_f32_16x16x32_bf16(
                            fA[kh * 3 + kw].b, fB[kw].b, a, 0, 0, 0);
                acc[kh] = a;
            }

            #pragma unroll
            for (int r = 0; r < 4; ++r) {
                float s = __fadd_rn(__fadd_rn(acc[0][r], acc[1][r]),
                                    __fadd_rn(acc[2][r], bias[r]));
                out[obase + ((size_t)r << 16) + ((size_t)y << 8)] = fmaxf(s, 0.f);
            }
        }
    }
}

extern "C" void kernel_launch(void* const* d_in, const int* in_sizes, int n_in,
                              void* d_out, int out_size, void* d_ws, size_t ws_size,
                              hipStream_t stream) {
    const float* x     = (const float*)d_in[0];
    const float* gamma = (const float*)d_in[1];
    const float* beta  = (const float*)d_in[2];
    const float* mean  = (const float*)d_in[3];
    const float* var   = (const float*)d_in[4];
    const float* w     = (const float*)d_in[5];
    const float* bias  = (const float*)d_in[6];
    float* o = (float*)d_out;

    dim3 grid(B_ * 8 * 8);   // 8 strips x 16 batches x 8 y-chunks = 1024
    dim3 block(256);
    hipLaunchKernelGGL(tbconv_kernel, grid, block, 0, stream,
                       x, gamma, beta, mean, var, w, bias, o);
}

// Round 7
// 338.979 us; speedup vs baseline: 1.2105x; 1.2105x over previous
//
#include <hip/hip_runtime.h>

// TBConv2d: BN -> ternary{-1,0,1} -> conv3x3(p=1) -> +bias -> ReLU
// v7: TWO-PASS SPLIT. R0-R6: every fused row-pipeline schedule (1-row, 2-row,
// light-barrier, wave-private) pinned at 103-122us; sustained in-flight
// ~3-7 KB/CU (Little) because the fused loop's load duty-cycle is tiny.
// Split into two streaming-shaped kernels, each occupancy/TLP-limited only:
//  pass1 quant_kernel: BN+ternary+transpose x -> Q (bf16, MFMA-B layout,
//    zero-padded px columns). No LDS, no barriers, float4 reads 1KB/instr.
//  pass2 conv_kernel: B-frags loaded DIRECTLY from global Q (dwordx4);
//    no LDS ring, no main-loop barriers; per wave 16 rows x {9 loads ->
//    9 MFMA -> 4 stores}; weights staged once in LDS (2 startup barriers).
// Traffic 404 MB total (vs 268 fused-ideal) but each pass can actually
// run at HBM speed instead of the fused pipeline's 2-3 TB/s.

#define B_    16
#define H_    256
#define W_    256
#define QROW  16512   // 258 px-slots * 64 B per (b,y) row
// Q layout: Q[(b*256+y)*QROW + px1*64 + oct*16 + cl*2] = bf16 ternary of
// x[b][ci=oct*8+cl][y][px1-1]; px1 = 0 and 257 are zero-pad columns
// (so pass2 needs no x-edge handling; y-edges skipped wave-uniformly).

typedef __bf16 bf16x8 __attribute__((ext_vector_type(8)));
typedef float  f32x4  __attribute__((ext_vector_type(4)));
union FragCast { int4 i; bf16x8 b; };

__device__ __forceinline__ unsigned short f2bf(float f) {
    union { float f; unsigned u; } c; c.f = f;
    unsigned u = c.u;
    u += 0x7FFFu + ((u >> 16) & 1u);      // RNE
    return (unsigned short)(u >> 16);
}

// torch semantics @thr=0: x <= -0 -> -1 (catches 0), else x >= 0 -> +1, NaN -> 0
__device__ __forceinline__ unsigned short quant1(float v, float sc, float sh) {
    float xh = __fadd_rn(__fmul_rn(v, sc), sh);   // exact numpy op order, no FMA
    return (xh <= 0.0f) ? (unsigned short)0xBF80u
         : ((xh >= 0.0f) ? (unsigned short)0x3F80u : (unsigned short)0u);
}

// ---------------- pass 1: BN + ternary quantize + transpose --------------
// block = one (b,y) row, 256 threads; wave o = ci-octet, lane q = px-quad.
// reads: 8 float4 loads/thread, wave-contiguous 1KB per instr.
// writes: 4 int4/thread; each 64B px-chunk fully written -> full sectors.
__launch_bounds__(256, 4)
__global__ void quant_kernel(const float* __restrict__ x,
                             const float* __restrict__ bn_g,
                             const float* __restrict__ bn_b,
                             const float* __restrict__ bn_m,
                             const float* __restrict__ bn_v,
                             unsigned char* __restrict__ Qb)
{
    const int tid = threadIdx.x;
    const int bx  = blockIdx.x;            // b*256 + y
    const int b = bx >> 8, y = bx & 255;
    const int o = tid >> 6;                // wave index = ci-octet (8o..8o+7)
    const int q = tid & 63;                // px quad: px = 4q..4q+3

    // per-octet BN scale/shift (ci wave-uniform -> scalarized loads)
    float sc[8], sh[8];
    #pragma unroll
    for (int c = 0; c < 8; ++c) {
        const int ci = 8 * o + c;
        float s = __fdiv_rn(bn_g[ci], __fsqrt_rn(__fadd_rn(bn_v[ci], 1e-4f)));
        sc[c] = s;
        sh[c] = __fsub_rn(bn_b[ci], __fmul_rn(bn_m[ci], s));
    }

    float4 vv[8];
    #pragma unroll
    for (int c = 0; c < 8; ++c)
        vv[c] = *(const float4*)(x + (((size_t)(b * 32 + 8 * o + c)) << 16)
                                   + (y << 8) + 4 * q);

    unsigned char* qrow = Qb + (size_t)(b * 256 + y) * QROW;
    #pragma unroll
    for (int i = 0; i < 4; ++i) {          // px = 4q + i -> px1 = 4q+1+i
        unsigned d[4];
        #pragma unroll
        for (int k = 0; k < 4; ++k) {      // ci pair (8o+2k, 8o+2k+1)
            const float v0 = ((const float*)&vv[2 * k    ])[i];
            const float v1 = ((const float*)&vv[2 * k + 1])[i];
            d[k] = (unsigned)quant1(v0, sc[2 * k],     sh[2 * k])
                 | ((unsigned)quant1(v1, sc[2 * k + 1], sh[2 * k + 1]) << 16);
        }
        int4 st; st.x = d[0]; st.y = d[1]; st.z = d[2]; st.w = d[3];
        *(int4*)(qrow + (size_t)(4 * q + 1 + i) * 64 + o * 16) = st;
    }
    // zero-pad columns px1 = 0 and 257 (represent gx = -1 and 256)
    if (q == 0) { int4 z = {0, 0, 0, 0}; *(int4*)(qrow + o * 16) = z; }
    if (q == 1) { int4 z = {0, 0, 0, 0}; *(int4*)(qrow + 257 * 64 + o * 16) = z; }
}

// ---------------- pass 2: conv3x3 + bias + ReLU, B-frags from global -----
// block = (b, ct, strip, yg) of 4 independent waves (wave -> y-chunk of 16
// rows). No LDS ring, no main-loop barriers; weights staged once in LDS.
__launch_bounds__(256, 4)
__global__ void conv_kernel(const float* __restrict__ conv_w,
                            const float* __restrict__ conv_b,
                            const unsigned char* __restrict__ Qb,
                            float* __restrict__ out)
{
    __shared__ __align__(16) unsigned int sW[4608];   // bf16 [tap][co][ci]

    const int tid = threadIdx.x;
    for (int j = tid; j < 4608; j += 256) {
        int cp = j & 15, co = (j >> 4) & 31, t = j >> 9;
        float w0 = conv_w[(co * 32 + 2 * cp)     * 9 + t];
        float w1 = conv_w[(co * 32 + 2 * cp + 1) * 9 + t];
        sW[j] = (unsigned)f2bf(w0) | ((unsigned)f2bf(w1) << 16);
    }
    __syncthreads();

    const int bx = blockIdx.x;             // (((b*2+ct)*16)+strip)*4 + yg
    const int yg    = bx & 3;
    const int strip = (bx >> 2) & 15;
    const int ct    = (bx >> 6) & 1;
    const int b     = bx >> 7;

    const int lane = tid & 63, wave = tid >> 6;
    const int oct = lane >> 4, n = lane & 15;
    const int yq = yg * 4 + wave;          // 0..15
    const int y0 = yq * 16;
    const int x0w = strip * 16;

    // persistent A-frags: A[m=co=ct*16+n][k=ci=oct*8+j] per tap
    FragCast fA[9];
    #pragma unroll
    for (int t = 0; t < 9; ++t)
        fA[t].i = *(const int4*)((const char*)sW +
                                 ((t * 32 + ct * 16 + n) * 32 + oct * 8) * 2);

    // per-lane B-frag byte offsets within a Q row (px1 = x0w + n + kw)
    int boff[3];
    #pragma unroll
    for (int kw = 0; kw < 3; ++kw)
        boff[kw] = (x0w + n + kw) * 64 + oct * 16;

    float bias[4];
    #pragma unroll
    for (int r = 0; r < 4; ++r)
        bias[r] = conv_b[ct * 16 + oct * 4 + r];
    const size_t obase = (((size_t)(b * 32 + ct * 16 + oct * 4)) << 16)
                       + ((size_t)y0 << 8) + (x0w + n);

    const unsigned char* qbb = Qb + (size_t)(b * 256) * QROW;

    for (int y = 0; y < 16; ++y) {
        const int gy = y0 + y;
        f32x4 acc = {0.f, 0.f, 0.f, 0.f};
        #pragma unroll
        for (int kh = 0; kh < 3; ++kh) {
            const int gr = gy + kh - 1;
            if ((unsigned)gr < (unsigned)H_) {      // wave-uniform y-edge skip
                const unsigned char* rp = qbb + (size_t)gr * QROW;
                FragCast f0, f1, f2;
                f0.i = *(const int4*)(rp + boff[0]);
                f1.i = *(const int4*)(rp + boff[1]);
                f2.i = *(const int4*)(rp + boff[2]);
                acc = __builtin_amdgcn_mfma_f32_16x16x32_bf16(fA[3*kh+0].b, f0.b, acc, 0, 0, 0);
                acc = __builtin_amdgcn_mfma_f32_16x16x32_bf16(fA[3*kh+1].b, f1.b, acc, 0, 0, 0);
                acc = __builtin_amdgcn_mfma_f32_16x16x32_bf16(fA[3*kh+2].b, f2.b, acc, 0, 0, 0);
            }
        }
        #pragma unroll
        for (int r = 0; r < 4; ++r) {
            float s = __fadd_rn(acc[r], bias[r]);
            out[obase + ((size_t)r << 16) + ((size_t)y << 8)] = fmaxf(s, 0.f);
        }
    }
}

extern "C" void kernel_launch(void* const* d_in, const int* in_sizes, int n_in,
                              void* d_out, int out_size, void* d_ws, size_t ws_size,
                              hipStream_t stream) {
    const float* x     = (const float*)d_in[0];
    const float* gamma = (const float*)d_in[1];
    const float* beta  = (const float*)d_in[2];
    const float* mean  = (const float*)d_in[3];
    const float* var   = (const float*)d_in[4];
    const float* w     = (const float*)d_in[5];
    const float* bias  = (const float*)d_in[6];
    float* o = (float*)d_out;

    unsigned char* Qb = (unsigned char*)d_ws;   // needs 16*256*QROW = 67.6 MB

    hipLaunchKernelGGL(quant_kernel, dim3(B_ * 256), dim3(256), 0, stream,
                       x, gamma, beta, mean, var, Qb);
    hipLaunchKernelGGL(conv_kernel, dim3(2048), dim3(256), 0, stream,
                       w, bias, Qb, o);
}